// Round 1
// baseline (300.919 us; speedup 1.0000x reference)
//
#include <hip/hip_runtime.h>
#include <math.h>

typedef _Float16 half8 __attribute__((ext_vector_type(8)));
typedef float f32x4 __attribute__((ext_vector_type(4)));

#define HDIM 128   // hidden width
#define FDIM 128   // node feature width

// ---------------------------------------------------------------------------
// Prep: convert x (N x 128 fp32) -> fp16, and pack W1/W2/W3 into MFMA B-frag
// order: frag(ct, ks) at Wp[((ct*KS + ks)*64 + lane)*8 + j] = W[k][n]
//   n = ct*16 + (lane&15), k = ks*32 + (lane>>4)*8 + j
// so the main kernel's B-frag load is one coalesced 16B load per lane.
// ---------------------------------------------------------------------------
__global__ __launch_bounds__(256) void prep_kernel(
    const float* __restrict__ x,  const float* __restrict__ W1,
    const float* __restrict__ W2, const float* __restrict__ W3,
    _Float16* __restrict__ xh,  _Float16* __restrict__ W1p,
    _Float16* __restrict__ W2p, _Float16* __restrict__ W3p, int NF)
{
    int bid = blockIdx.x;
    if (bid < 32) {
        int t = bid * 256 + threadIdx.x;   // 0..8191
        const float* W; _Float16* Wp; int KS; int u;
        if (t < 4096)      { W = W1; Wp = W1p; KS = 8; u = t; }          // 256x128
        else if (t < 6144) { W = W2; Wp = W2p; KS = 4; u = t - 4096; }   // 128x128
        else               { W = W3; Wp = W3p; KS = 4; u = t - 6144; }   // 128x128
        int lane = u & 63;
        int fk   = u >> 6;            // ct*KS + ks
        int ks   = fk % KS;
        int ct   = fk / KS;
        int n    = ct * 16 + (lane & 15);
        int k0   = ks * 32 + (lane >> 4) * 8;
        half8 v;
        #pragma unroll
        for (int j = 0; j < 8; ++j) v[j] = (_Float16)W[(k0 + j) * HDIM + n];
        *(half8*)(Wp + (size_t)u * 8) = v;
    } else {
        long i = (long)(bid - 32) * 2048 + (long)threadIdx.x * 8;
        if (i + 8 <= (long)NF) {
            const float4* xf = (const float4*)(x + i);
            float4 f0 = xf[0], f1 = xf[1];
            half8 v;
            v[0] = (_Float16)f0.x; v[1] = (_Float16)f0.y;
            v[2] = (_Float16)f0.z; v[3] = (_Float16)f0.w;
            v[4] = (_Float16)f1.x; v[5] = (_Float16)f1.y;
            v[6] = (_Float16)f1.z; v[7] = (_Float16)f1.w;
            *(half8*)(xh + i) = v;
        }
    }
}

// ---------------------------------------------------------------------------
// Fused edge-MLP. One block = 256 threads = 4 waves; each wave owns 32 edges
// (2 MFMA row-tiles) end-to-end. No __syncthreads: each wave only touches its
// own 32-row slice of the LDS h buffer.
// MFMA 16x16x32 f16 layouts (HW-verified per guide):
//   A: lane holds A[m=lane&15][k=(lane>>4)*8 + j], j=0..7  (16B contiguous)
//   B: lane holds B[k=(lane>>4)*8 + j][n=lane&15]          (packed by prep)
//   C/D: lane holds D[(lane>>4)*4 + r][lane&15], r=0..3
// ---------------------------------------------------------------------------
__global__ __launch_bounds__(256, 2) void edge_mlp_kernel(
    const int* __restrict__ ei,          // (2, E) int32
    const _Float16* __restrict__ xh,     // (N, 128) fp16
    const _Float16* __restrict__ W1p,    // packed frags
    const _Float16* __restrict__ W2p,
    const _Float16* __restrict__ W3p,
    const float* __restrict__ b1, const float* __restrict__ b2,
    const float* __restrict__ b3, const float* __restrict__ W4,
    const float* __restrict__ b4,
    float* __restrict__ out, int E)
{
    // 128 rows x 136 halfs: stride 272B -> 16B-aligned b128 reads, 2-way bank
    // aliasing only (free per m136).
    __shared__ _Float16 hbuf[128 * 136];

    const int tid  = threadIdx.x;
    const int wave = tid >> 6;
    const int lane = tid & 63;
    const int l15  = lane & 15;
    const int quad = lane >> 4;

    const int base = blockIdx.x * 128 + wave * 32;
    const int r0   = base + l15;           // row for rt=0, this lane
    const int r1   = base + 16 + l15;      // row for rt=1
    const int cr0  = min(r0, E - 1);
    const int cr1  = min(r1, E - 1);

    const int e00 = ei[cr0];               // x_i index (edge_index[0])
    const int e01 = ei[cr1];
    const int e10 = ei[E + cr0];           // x_j index (edge_index[1])
    const int e11 = ei[E + cr1];

    f32x4 acc[2][8];
    #pragma unroll
    for (int rt = 0; rt < 2; ++rt)
        #pragma unroll
        for (int ct = 0; ct < 8; ++ct) acc[rt][ct] = f32x4{0.f, 0.f, 0.f, 0.f};

    // ---------------- Layer 1: [x_i | x_j] (Kglobal=256) @ W1 ----------------
    #pragma unroll
    for (int hf = 0; hf < 2; ++hf) {
        const _Float16* p0 = xh + (size_t)(hf ? e10 : e00) * FDIM;
        const _Float16* p1 = xh + (size_t)(hf ? e11 : e01) * FDIM;
        half8 a0[4], a1[4];
        #pragma unroll
        for (int ks = 0; ks < 4; ++ks) {
            a0[ks] = *(const half8*)(p0 + ks * 32 + quad * 8);
            a1[ks] = *(const half8*)(p1 + ks * 32 + quad * 8);
        }
        #pragma unroll
        for (int ks = 0; ks < 4; ++ks) {
            const int kk = hf * 4 + ks;
            #pragma unroll
            for (int ct = 0; ct < 8; ++ct) {
                half8 b = *(const half8*)(W1p + (size_t)((ct * 8 + kk) * 64 + lane) * 8);
                acc[0][ct] = __builtin_amdgcn_mfma_f32_16x16x32_f16(a0[ks], b, acc[0][ct], 0, 0, 0);
                acc[1][ct] = __builtin_amdgcn_mfma_f32_16x16x32_f16(a1[ks], b, acc[1][ct], 0, 0, 0);
            }
        }
    }

    // epilogue 1: h1 = relu(acc + b1) -> LDS (fp16), reset acc
    #pragma unroll
    for (int rt = 0; rt < 2; ++rt) {
        #pragma unroll
        for (int ct = 0; ct < 8; ++ct) {
            const int col = ct * 16 + l15;
            const float bias = b1[col];
            #pragma unroll
            for (int r = 0; r < 4; ++r) {
                float w = fmaxf(acc[rt][ct][r] + bias, 0.f);
                hbuf[(wave * 32 + rt * 16 + quad * 4 + r) * 136 + col] = (_Float16)w;
            }
            acc[rt][ct] = f32x4{0.f, 0.f, 0.f, 0.f};
        }
    }

    // ---------------- Layer 2: h1 @ W2 ----------------
    #pragma unroll
    for (int ks = 0; ks < 4; ++ks) {
        half8 a0 = *(const half8*)&hbuf[(wave * 32 + l15) * 136 + ks * 32 + quad * 8];
        half8 a1 = *(const half8*)&hbuf[(wave * 32 + 16 + l15) * 136 + ks * 32 + quad * 8];
        #pragma unroll
        for (int ct = 0; ct < 8; ++ct) {
            half8 b = *(const half8*)(W2p + (size_t)((ct * 4 + ks) * 64 + lane) * 8);
            acc[0][ct] = __builtin_amdgcn_mfma_f32_16x16x32_f16(a0, b, acc[0][ct], 0, 0, 0);
            acc[1][ct] = __builtin_amdgcn_mfma_f32_16x16x32_f16(a1, b, acc[1][ct], 0, 0, 0);
        }
    }

    // epilogue 2: h2 = relu(acc + b2) -> LDS, reset acc
    #pragma unroll
    for (int rt = 0; rt < 2; ++rt) {
        #pragma unroll
        for (int ct = 0; ct < 8; ++ct) {
            const int col = ct * 16 + l15;
            const float bias = b2[col];
            #pragma unroll
            for (int r = 0; r < 4; ++r) {
                float w = fmaxf(acc[rt][ct][r] + bias, 0.f);
                hbuf[(wave * 32 + rt * 16 + quad * 4 + r) * 136 + col] = (_Float16)w;
            }
            acc[rt][ct] = f32x4{0.f, 0.f, 0.f, 0.f};
        }
    }

    // ---------------- Layer 3: h2 @ W3 ----------------
    #pragma unroll
    for (int ks = 0; ks < 4; ++ks) {
        half8 a0 = *(const half8*)&hbuf[(wave * 32 + l15) * 136 + ks * 32 + quad * 8];
        half8 a1 = *(const half8*)&hbuf[(wave * 32 + 16 + l15) * 136 + ks * 32 + quad * 8];
        #pragma unroll
        for (int ct = 0; ct < 8; ++ct) {
            half8 b = *(const half8*)(W3p + (size_t)((ct * 4 + ks) * 64 + lane) * 8);
            acc[0][ct] = __builtin_amdgcn_mfma_f32_16x16x32_f16(a0, b, acc[0][ct], 0, 0, 0);
            acc[1][ct] = __builtin_amdgcn_mfma_f32_16x16x32_f16(a1, b, acc[1][ct], 0, 0, 0);
        }
    }

    // ---------------- Layer 4: sigmoid(relu(acc + b3) @ W4 + b4), in-register
    const float b4v = b4[0];
    #pragma unroll
    for (int rt = 0; rt < 2; ++rt) {
        float s0 = 0.f, s1 = 0.f, s2 = 0.f, s3 = 0.f;
        #pragma unroll
        for (int ct = 0; ct < 8; ++ct) {
            const int col = ct * 16 + l15;
            const float bias = b3[col];
            const float wv   = W4[col];
            f32x4 v = acc[rt][ct];
            s0 += fmaxf(v[0] + bias, 0.f) * wv;
            s1 += fmaxf(v[1] + bias, 0.f) * wv;
            s2 += fmaxf(v[2] + bias, 0.f) * wv;
            s3 += fmaxf(v[3] + bias, 0.f) * wv;
        }
        // reduce over the 16 lanes of this quad (cols)
        #pragma unroll
        for (int m = 1; m < 16; m <<= 1) {
            s0 += __shfl_xor(s0, m, 64);
            s1 += __shfl_xor(s1, m, 64);
            s2 += __shfl_xor(s2, m, 64);
            s3 += __shfl_xor(s3, m, 64);
        }
        if (l15 == 0) {
            const int rowb = base + rt * 16 + quad * 4;
            float ss[4] = {s0, s1, s2, s3};
            #pragma unroll
            for (int r = 0; r < 4; ++r) {
                const int row = rowb + r;
                if (row < E) out[row] = 1.f / (1.f + __expf(-(ss[r] + b4v)));
            }
        }
    }
}

// ---------------------------------------------------------------------------
extern "C" void kernel_launch(void* const* d_in, const int* in_sizes, int n_in,
                              void* d_out, int out_size, void* d_ws, size_t ws_size,
                              hipStream_t stream)
{
    const float* x  = (const float*)d_in[0];
    const int*   ei = (const int*)d_in[1];
    const float* W1 = (const float*)d_in[2];
    const float* b1 = (const float*)d_in[3];
    const float* W2 = (const float*)d_in[4];
    const float* b2 = (const float*)d_in[5];
    const float* W3 = (const float*)d_in[6];
    const float* b3 = (const float*)d_in[7];
    const float* W4 = (const float*)d_in[8];
    const float* b4 = (const float*)d_in[9];
    float* out = (float*)d_out;

    const int NF = in_sizes[0];    // N*F = 12,800,000
    const int E  = out_size;       // 625,000

    // workspace layout (fp16): [ xh : NF ][ W1p : 32768 ][ W2p : 16384 ][ W3p : 16384 ]
    _Float16* xh  = (_Float16*)d_ws;
    _Float16* W1p = xh + NF;
    _Float16* W2p = W1p + 32768;
    _Float16* W3p = W2p + 16384;

    const int xblocks = (NF + 2047) / 2048;
    prep_kernel<<<32 + xblocks, 256, 0, stream>>>(x, W1, W2, W3, xh, W1p, W2p, W3p, NF);

    const int grid = (E + 127) / 128;
    edge_mlp_kernel<<<grid, 256, 0, stream>>>(ei, xh, W1p, W2p, W3p,
                                              b1, b2, b3, W4, b4, out, E);
}

// Round 2
// 237.043 us; speedup vs baseline: 1.2695x; 1.2695x over previous
//
#include <hip/hip_runtime.h>
#include <math.h>

typedef _Float16 half8 __attribute__((ext_vector_type(8)));
typedef _Float16 half4 __attribute__((ext_vector_type(4)));
typedef float f32x4 __attribute__((ext_vector_type(4)));

#define HDIM 128
#define SSTR 136                          // scratch row stride in halfs (272 B, 16B-aligned)
#define WHALFS 65536                      // packed W1|W2|W3 total halfs (128 KB)
#define LDS_HALFS (WHALFS + 4 * 16 * SSTR)  // 74240 halfs
#define LDS_BYTES (LDS_HALFS * 2)           // 148480 B  (<= 160 KiB/CU)

// ---------------------------------------------------------------------------
// Prep: x (N x 128 fp32) -> fp16; pack W1/W2/W3 into MFMA *A-operand* frag
// order for the transposed GEMM (A = W^T):
//   frag(ct,ks), lane: A[m=ct*16+(lane&15)][k=ks*32+(lane>>4)*8+j] = W[k][m]
// identical memory pattern to round 1's pack.
// ---------------------------------------------------------------------------
__global__ __launch_bounds__(256) void prep_kernel(
    const float* __restrict__ x,  const float* __restrict__ W1,
    const float* __restrict__ W2, const float* __restrict__ W3,
    _Float16* __restrict__ xh,  _Float16* __restrict__ W1p,
    _Float16* __restrict__ W2p, _Float16* __restrict__ W3p, int NF)
{
    int bid = blockIdx.x;
    if (bid < 32) {
        int t = bid * 256 + threadIdx.x;   // 0..8191
        const float* W; _Float16* Wp; int KS; int u;
        if (t < 4096)      { W = W1; Wp = W1p; KS = 8; u = t; }          // 256x128
        else if (t < 6144) { W = W2; Wp = W2p; KS = 4; u = t - 4096; }   // 128x128
        else               { W = W3; Wp = W3p; KS = 4; u = t - 6144; }   // 128x128
        int lane = u & 63;
        int fk   = u >> 6;            // ct*KS + ks
        int ks   = fk % KS;
        int ct   = fk / KS;
        int m    = ct * 16 + (lane & 15);
        int k0   = ks * 32 + (lane >> 4) * 8;
        half8 v;
        #pragma unroll
        for (int j = 0; j < 8; ++j) v[j] = (_Float16)W[(k0 + j) * HDIM + m];
        *(half8*)(Wp + (size_t)u * 8) = v;
    } else {
        long i = (long)(bid - 32) * 2048 + (long)threadIdx.x * 8;
        if (i + 8 <= (long)NF) {
            const float4* xf = (const float4*)(x + i);
            float4 f0 = xf[0], f1 = xf[1];
            half8 v;
            v[0] = (_Float16)f0.x; v[1] = (_Float16)f0.y;
            v[2] = (_Float16)f0.z; v[3] = (_Float16)f0.w;
            v[4] = (_Float16)f1.x; v[5] = (_Float16)f1.y;
            v[6] = (_Float16)f1.z; v[7] = (_Float16)f1.w;
            *(half8*)(xh + i) = v;
        }
    }
}

// ---------------------------------------------------------------------------
// Epilogue: relu(acc + bias) -> fp16 scratch [edge(l15)][hidden], then pull
// next layer's B-frags (B[k=hidden][n=edge]) back as b128. Scratch is a
// single 16-edge tile per wave, serially reused across nt (exact-address
// deps keep the compiler honest). Resets acc.
// ---------------------------------------------------------------------------
__device__ __forceinline__ void epi_extract(
    f32x4 (&acc)[4][8], const float* __restrict__ bias,
    _Float16* __restrict__ scr, int l15, int quad, half8 (&bh)[4][4])
{
    float4 bv[8];
    #pragma unroll
    for (int ct = 0; ct < 8; ++ct)
        bv[ct] = *(const float4*)(bias + ct * 16 + quad * 4);
    #pragma unroll
    for (int nt = 0; nt < 4; ++nt) {
        #pragma unroll
        for (int ct = 0; ct < 8; ++ct) {
            half4 h;
            h[0] = (_Float16)fmaxf(acc[nt][ct][0] + bv[ct].x, 0.f);
            h[1] = (_Float16)fmaxf(acc[nt][ct][1] + bv[ct].y, 0.f);
            h[2] = (_Float16)fmaxf(acc[nt][ct][2] + bv[ct].z, 0.f);
            h[3] = (_Float16)fmaxf(acc[nt][ct][3] + bv[ct].w, 0.f);
            *(half4*)(scr + l15 * SSTR + ct * 16 + quad * 4) = h;   // ds_write_b64
            acc[nt][ct] = f32x4{0.f, 0.f, 0.f, 0.f};
        }
        #pragma unroll
        for (int ks = 0; ks < 4; ++ks)                               // ds_read_b128
            bh[nt][ks] = *(const half8*)(scr + l15 * SSTR + ks * 32 + quad * 8);
    }
}

__device__ __forceinline__ void layer_mfma(
    f32x4 (&acc)[4][8], const _Float16* __restrict__ Wl,
    half8 (&bh)[4][4], int lane)
{
    #pragma unroll
    for (int ks = 0; ks < 4; ++ks) {
        half8 aw[8];
        #pragma unroll
        for (int ct = 0; ct < 8; ++ct)
            aw[ct] = *(const half8*)(Wl + ((size_t)((ct * 4 + ks) * 64 + lane)) * 8);
        #pragma unroll
        for (int nt = 0; nt < 4; ++nt)
            #pragma unroll
            for (int ct = 0; ct < 8; ++ct)
                acc[nt][ct] = __builtin_amdgcn_mfma_f32_16x16x32_f16(
                    aw[ct], bh[nt][ks], acc[nt][ct], 0, 0, 0);
    }
}

// ---------------------------------------------------------------------------
// Persistent fused MLP, transposed GEMM: D[hidden][edge] = W^T (A) x ef^T (B).
// grid = 256 blocks x 256 thr; 145 KB LDS -> 1 block/CU; each wave owns 64
// edges (4 n-tiles of 16) per tile iteration. All weights live in LDS.
// ---------------------------------------------------------------------------
__global__ __launch_bounds__(256, 1) void edge_mlp_kernel(
    const int* __restrict__ ei, const _Float16* __restrict__ xh,
    const _Float16* __restrict__ wpack,   // W1p|W2p|W3p contiguous, 65536 halfs
    const float* __restrict__ b1, const float* __restrict__ b2,
    const float* __restrict__ b3, const float* __restrict__ W4,
    const float* __restrict__ b4, float* __restrict__ out, int E)
{
    extern __shared__ _Float16 lds[];

    // stage 128 KB of packed weights, once per (persistent) block
    {
        float4* dst = (float4*)lds;
        const float4* src = (const float4*)wpack;
        #pragma unroll
        for (int i = 0; i < 32; ++i)
            dst[i * 256 + threadIdx.x] = src[i * 256 + threadIdx.x];
    }
    __syncthreads();

    const int tid  = threadIdx.x;
    const int wave = tid >> 6;
    const int lane = tid & 63;
    const int l15  = lane & 15;
    const int quad = lane >> 4;

    const _Float16* W1l = lds;
    const _Float16* W2l = lds + 32768;
    const _Float16* W3l = lds + 49152;
    _Float16* scr = lds + WHALFS + wave * (16 * SSTR);

    const int ntiles = (E + 255) >> 8;
    const float b4v = b4[0];

    for (int t = blockIdx.x; t < ntiles; t += gridDim.x) {
        const int base = t * 256 + wave * 64;

        // ---- gather layer-1 B-frags: B[k=concat-feat][n=edge] ----
        half8 bef[4][8];
        #pragma unroll
        for (int nt = 0; nt < 4; ++nt) {
            const int row = min(base + nt * 16 + l15, E - 1);
            const _Float16* pi = xh + (size_t)ei[row] * HDIM;
            const _Float16* pj = xh + (size_t)ei[E + row] * HDIM;
            #pragma unroll
            for (int ks = 0; ks < 4; ++ks) {
                bef[nt][ks]     = *(const half8*)(pi + ks * 32 + quad * 8);
                bef[nt][4 + ks] = *(const half8*)(pj + ks * 32 + quad * 8);
            }
        }

        f32x4 acc[4][8];
        #pragma unroll
        for (int nt = 0; nt < 4; ++nt)
            #pragma unroll
            for (int ct = 0; ct < 8; ++ct) acc[nt][ct] = f32x4{0.f, 0.f, 0.f, 0.f};

        // ---- layer 1: K=256 ----
        #pragma unroll
        for (int ks = 0; ks < 8; ++ks) {
            half8 aw[8];
            #pragma unroll
            for (int ct = 0; ct < 8; ++ct)
                aw[ct] = *(const half8*)(W1l + ((size_t)((ct * 8 + ks) * 64 + lane)) * 8);
            #pragma unroll
            for (int nt = 0; nt < 4; ++nt)
                #pragma unroll
                for (int ct = 0; ct < 8; ++ct)
                    acc[nt][ct] = __builtin_amdgcn_mfma_f32_16x16x32_f16(
                        aw[ct], bef[nt][ks], acc[nt][ct], 0, 0, 0);
        }

        half8 bh[4][4];
        epi_extract(acc, b1, scr, l15, quad, bh);     // h1 -> B-frags
        layer_mfma(acc, W2l, bh, lane);               // layer 2
        epi_extract(acc, b2, scr, l15, quad, bh);     // h2 -> B-frags
        layer_mfma(acc, W3l, bh, lane);               // layer 3

        // ---- layer 4: per-edge dot over hidden + sigmoid ----
        #pragma unroll
        for (int nt = 0; nt < 4; ++nt) {
            float s = 0.f;
            #pragma unroll
            for (int ct = 0; ct < 8; ++ct) {
                float4 b3v = *(const float4*)(b3 + ct * 16 + quad * 4);
                float4 w4v = *(const float4*)(W4 + ct * 16 + quad * 4);
                s += fmaxf(acc[nt][ct][0] + b3v.x, 0.f) * w4v.x;
                s += fmaxf(acc[nt][ct][1] + b3v.y, 0.f) * w4v.y;
                s += fmaxf(acc[nt][ct][2] + b3v.z, 0.f) * w4v.z;
                s += fmaxf(acc[nt][ct][3] + b3v.w, 0.f) * w4v.w;
            }
            s += __shfl_xor(s, 16, 64);   // sum across quads (same l15)
            s += __shfl_xor(s, 32, 64);
            const int row = base + nt * 16 + l15;
            if (quad == 0 && row < E)
                out[row] = 1.f / (1.f + __expf(-(s + b4v)));
        }
    }
}

// ---------------------------------------------------------------------------
extern "C" void kernel_launch(void* const* d_in, const int* in_sizes, int n_in,
                              void* d_out, int out_size, void* d_ws, size_t ws_size,
                              hipStream_t stream)
{
    const float* x  = (const float*)d_in[0];
    const int*   ei = (const int*)d_in[1];
    const float* W1 = (const float*)d_in[2];
    const float* b1 = (const float*)d_in[3];
    const float* W2 = (const float*)d_in[4];
    const float* b2 = (const float*)d_in[5];
    const float* W3 = (const float*)d_in[6];
    const float* b3 = (const float*)d_in[7];
    const float* W4 = (const float*)d_in[8];
    const float* b4 = (const float*)d_in[9];
    float* out = (float*)d_out;

    const int NF = in_sizes[0];    // N*F = 12,800,000
    const int E  = out_size;       // 625,000

    // ws layout (halfs): [ xh : NF ][ W1p : 32768 ][ W2p : 16384 ][ W3p : 16384 ]
    _Float16* xh  = (_Float16*)d_ws;
    _Float16* W1p = xh + NF;
    _Float16* W2p = W1p + 32768;
    _Float16* W3p = W2p + 16384;

    const int xblocks = (NF + 2047) / 2048;
    prep_kernel<<<32 + xblocks, 256, 0, stream>>>(x, W1, W2, W3, xh, W1p, W2p, W3p, NF);

    hipFuncSetAttribute((const void*)edge_mlp_kernel,
                        hipFuncAttributeMaxDynamicSharedMemorySize, LDS_BYTES);
    edge_mlp_kernel<<<256, 256, LDS_BYTES, stream>>>(ei, xh, W1p,
                                                     b1, b2, b3, W4, b4, out, E);
}